// Round 8
// baseline (275.495 us; speedup 1.0000x reference)
//
#include <hip/hip_runtime.h>
#include <stdint.h>

#define D_MODEL 2048
#define N_HEAD 32
#define N_KV_HEAD 8
#define HEAD_DIM 64
#define BATCH 2
#define SEQ 2048
#define ROWS (BATCH*SEQ)   // 4096
#define QKV_N 3072         // fused projection width: Q 0..2047 | K 2048..2559 | V 2560..3071

typedef __attribute__((ext_vector_type(4))) float f32x4;
typedef __attribute__((ext_vector_type(16))) float f32x16;
typedef __attribute__((ext_vector_type(8))) short bf16x8;

__device__ __forceinline__ float bflo(unsigned u){ return __uint_as_float(u << 16); }
__device__ __forceinline__ float bfhi(unsigned u){ return __uint_as_float(u & 0xFFFF0000u); }
__device__ __forceinline__ unsigned f2bf(float f){
  unsigned u = __float_as_uint(f);
  u += 0x7FFFu + ((u >> 16) & 1u);
  return u >> 16;   // RNE bf16 in low 16 bits
}
// packed f32x2 -> bf16x2 (RNE), single HW instr on gfx950
__device__ __forceinline__ unsigned cvtpk(float a, float b){
  unsigned r;
  asm("v_cvt_pk_bf16_f32 %0, %1, %2" : "=v"(r) : "v"(a), "v"(b));
  return r;
}

__device__ __forceinline__ f32x16 mfma32(bf16x8 a, bf16x8 b, f32x16 c){
  return __builtin_amdgcn_mfma_f32_32x32x16_bf16(a, b, c, 0, 0, 0);
}

__device__ __forceinline__ void async_copy16(const void* g, void* lds){
  __builtin_amdgcn_global_load_lds(
      (const __attribute__((address_space(1))) void*)g,
      (__attribute__((address_space(3))) void*)lds, 16, 0, 0);
}

// Build PV B-operand fragment (k = 8*hi + j) from 8 post-exp2 f32 values held as
// C-layout rows (reg&3)+8*(reg>>2)+4*hi. 4 cvt_pk + 2 permlane32_swap. (T12/m214)
// NOTE: inputs to the two swap operands are DISTINCT values (no register-alias hazard).
#define MKFRAG(SV, RB, OUT) {                                   \
  unsigned a0_ = cvtpk(SV[RB+0], SV[RB+1]);                     \
  unsigned b0_ = cvtpk(SV[RB+4], SV[RB+5]);                     \
  unsigned a1_ = cvtpk(SV[RB+2], SV[RB+3]);                     \
  unsigned b1_ = cvtpk(SV[RB+6], SV[RB+7]);                     \
  asm("v_permlane32_swap_b32 %0, %1" : "+v"(a0_), "+v"(b0_));   \
  asm("v_permlane32_swap_b32 %0, %1" : "+v"(a1_), "+v"(b1_));   \
  union { unsigned u[4]; bf16x8 h; } c_;                        \
  c_.u[0]=a0_; c_.u[1]=a1_; c_.u[2]=b0_; c_.u[3]=b1_;           \
  OUT = c_.h; }

// ---------------- fp32 -> bf16 elementwise ----------------
__global__ __launch_bounds__(256) void k_cvt_bf16(const float* __restrict__ in,
                                                  unsigned short* __restrict__ out, int n4){
  int i = blockIdx.x*256 + threadIdx.x;
  if (i >= n4) return;
  float4 v = ((const float4*)in)[i];
  unsigned lo = f2bf(v.x) | (f2bf(v.y) << 16);
  unsigned hi = f2bf(v.z) | (f2bf(v.w) << 16);
  ((uint2*)out)[i] = make_uint2(lo, hi);
}

// ---------------- W[K][N] fp32 -> Wt[N][K] bf16 (64x64 LDS tiles) ----------------
__global__ __launch_bounds__(256) void k_transpose_bf16(const float* __restrict__ W,
                                                        unsigned short* __restrict__ Wt,
                                                        int K, int N){
  __shared__ float tile[64][65];
  const int ntn = N >> 6;
  const int tk = blockIdx.x / ntn, tn = blockIdx.x % ntn;
  const int tid = threadIdx.x;
  #pragma unroll
  for (int i = 0; i < 4; ++i) {
    int idx4 = tid + 256*i;          // 0..1023 float4s
    int r = idx4 >> 4;
    int c4 = idx4 & 15;
    float4 v = *(const float4*)(W + (size_t)(tk*64 + r)*N + tn*64 + c4*4);
    tile[r][c4*4+0] = v.x; tile[r][c4*4+1] = v.y;
    tile[r][c4*4+2] = v.z; tile[r][c4*4+3] = v.w;
  }
  __syncthreads();
  #pragma unroll
  for (int i = 0; i < 8; ++i) {
    int o2 = tid + 256*i;            // 0..2047 bf16 pairs
    int n  = o2 >> 5;
    int k2 = o2 & 31;
    unsigned lo = f2bf(tile[k2*2+0][n]);
    unsigned hi = f2bf(tile[k2*2+1][n]);
    *(unsigned*)(Wt + (size_t)(tn*64 + n)*K + tk*64 + k2*2) = lo | (hi << 16);
  }
}

// ---------------- RoPE tables: [SEQ][32] cos & sin ----------------
__global__ __launch_bounds__(256) void k_rope_tables(float* __restrict__ ct, float* __restrict__ st){
  int gid = blockIdx.x*256 + threadIdx.x;   // SEQ*32
  int t = gid >> 5, d = gid & 31;
  float inv = exp2f(-13.287712379549449f * ((float)d * (1.0f/32.0f)));  // 10000^(-d/32)
  float a = (float)t * inv;
  ct[gid] = cosf(a);
  st[gid] = sinf(a);
}

// ---------------- RoPE in-place; thread = (row, head); optional output scale ----------------
__global__ __launch_bounds__(256) void k_rope_apply(unsigned short* __restrict__ X,
                                                    const float* __restrict__ ct,
                                                    const float* __restrict__ st,
                                                    int nheads, int stride, float scale){
  int gid = blockIdx.x*256 + threadIdx.x;
  int row = gid / nheads;
  int h = gid - row*nheads;
  int t = row & (SEQ-1);
  unsigned* p = (unsigned*)(X + (size_t)row*stride + h*HEAD_DIM);
  float o1[32], o2[32];
  #pragma unroll
  for (int d = 0; d < 32; ++d) {
    unsigned u = p[d];
    float x1 = bflo(u), x2 = bfhi(u);
    float c = ct[t*32+d], s = st[t*32+d];
    o1[d] = (x1*c - x2*s)*scale;
    o2[d] = (x1*s + x2*c)*scale;
  }
  #pragma unroll
  for (int i = 0; i < 16; ++i) {
    p[i]    = f2bf(o1[2*i]) | (f2bf(o1[2*i+1]) << 16);
    p[16+i] = f2bf(o2[2*i]) | (f2bf(o2[2*i+1]) << 16);
  }
}

// ---------------- bf16 GEMM: C[M][N] = A[M][K] * Bt[N][K]^T ----------------
template<typename OUT_T>
__global__ __launch_bounds__(256) void k_gemm_bt(const unsigned short* __restrict__ A,
                                                 const unsigned short* __restrict__ Bt,
                                                 OUT_T* __restrict__ C,
                                                 int M, int N, int K){
  __shared__ unsigned short As[128*32];
  __shared__ unsigned short Bs[128*32];
  const int nbn = N >> 7;
  const int bm = blockIdx.x / nbn, bn = blockIdx.x % nbn;
  const int m0 = bm << 7, n0 = bn << 7;
  const int tid = threadIdx.x;
  const int wid = tid >> 6, lane = tid & 63;
  const int wr = wid >> 1, wc = wid & 1;

  f32x4 acc[4][4] = {};

  const int ldr = lane >> 2;
  const int ldc = (lane & 3) * 8;
  const int fr  = lane & 15;
  const int fk  = (lane >> 4) * 8;

  for (int k0 = 0; k0 < K; k0 += 32) {
    #pragma unroll
    for (int i = 0; i < 2; ++i) {
      int chunk = wid*2 + i;
      int row = chunk*16 + ldr;
      async_copy16(A  + (size_t)(m0+row)*K + k0 + ldc, (void*)(As + chunk*512));
      async_copy16(Bt + (size_t)(n0+row)*K + k0 + ldc, (void*)(Bs + chunk*512));
    }
    __syncthreads();
    bf16x8 a[4], b[4];
    #pragma unroll
    for (int m = 0; m < 4; ++m) a[m] = *(const bf16x8*)(As + (wr*64 + m*16 + fr)*32 + fk);
    #pragma unroll
    for (int n = 0; n < 4; ++n) b[n] = *(const bf16x8*)(Bs + (wc*64 + n*16 + fr)*32 + fk);
    #pragma unroll
    for (int m = 0; m < 4; ++m)
      #pragma unroll
      for (int n = 0; n < 4; ++n)
        acc[m][n] = __builtin_amdgcn_mfma_f32_16x16x32_bf16(a[m], b[n], acc[m][n], 0, 0, 0);
    __syncthreads();
  }

  const int crow = (lane >> 4) * 4, ccol = lane & 15;
  #pragma unroll
  for (int m = 0; m < 4; ++m){
    #pragma unroll
    for (int n = 0; n < 4; ++n){
      size_t base = (size_t)(m0 + wr*64 + m*16 + crow)*N + (n0 + wc*64 + n*16 + ccol);
      #pragma unroll
      for (int j = 0; j < 4; ++j){
        float v = acc[m][n][j];
        if constexpr (sizeof(OUT_T) == 2)
          ((unsigned short*)C)[base + (size_t)j*N] = (unsigned short)f2bf(v);
        else
          ((float*)C)[base + (size_t)j*N] = v;
      }
    }
  }
}

// ---------------- V transpose: Vsrc[b*SEQ+s][kvh*64+d] (stride) -> Vt[(b*8+kvh)*64+d][s] ----------------
__global__ __launch_bounds__(256) void k_transpose_v(const unsigned short* __restrict__ Vsrc,
                                                     unsigned short* __restrict__ Vt, int stride){
  __shared__ __align__(16) unsigned short t[64*64];
  const int bk = blockIdx.x >> 5;    // b*8+kvh
  const int st = blockIdx.x & 31;    // s-tile
  const int b = bk >> 3, kvh = bk & 7;
  const int tid = threadIdx.x;
  #pragma unroll
  for (int it = 0; it < 2; ++it) {
    int i = tid + 256*it;            // 0..511 16B chunks
    int s = i >> 3, c = i & 7;
    uint4 v = *(const uint4*)(Vsrc + (size_t)(b*SEQ + st*64 + s)*stride + kvh*HEAD_DIM + c*8);
    *(uint4*)(t + s*64 + ((c ^ (s&7))*8)) = v;   // chunk-swizzled store
  }
  __syncthreads();
  const int d = tid & 63;
  const int w = tid >> 6;
  #pragma unroll
  for (int it = 0; it < 2; ++it) {
    int seg = w + it*4;              // s-chunk of 8
    unsigned short tmp[8];
    #pragma unroll
    for (int k = 0; k < 8; ++k) {
      int s = seg*8 + k;
      tmp[k] = t[s*64 + (((d>>3) ^ (s&7))*8) + (d&7)];
    }
    *(uint4*)(Vt + ((size_t)bk*64 + d)*SEQ + st*64 + seg*8) = *(uint4*)tmp;
  }
}

// ---------------- MFMA flash attention: persistent blocks + dynamic work queue ----------------
// 1024 work items = (b, h, 128-row q-tile), causal-longest-first; grid = 768 blocks (3/CU,
// 12 waves/CU) claim items via atomicAdd -> first 768 fill the GPU, shortest 256 backfill.
// Deterministic: each item writes disjoint O rows; numerics independent of claimer.
// Per item: wave = 32 q rows (4 waves = 128). Swapped QK^T via mfma_32x32x16 (A=K, B=Q):
// lane holds 32 of 64 s for ONE q (partner lane^32 has the rest). Softmax in-register,
// log2 domain (Q pre-scaled), defer-max; P -> PV B-operand via cvt_pk + permlane32_swap.
// Cross-half reductions via __shfl_xor(.,32) (round-6-proven; permlane same-value
// helper had a register-alias miscompile hazard -> reverted).
// LDS: K dbuf 2x8K | V 8K = 24KB; epilogue reuses K region.
__global__ __launch_bounds__(256) void k_attn_mfma(const unsigned short* __restrict__ Q,
                                                   const unsigned short* __restrict__ Kb,
                                                   const unsigned short* __restrict__ Vt,
                                                   unsigned short* __restrict__ O,
                                                   const int* __restrict__ maskp,
                                                   unsigned* __restrict__ wq){
  __shared__ __align__(16) char smem[24576];   // K0 8K | K1 8K | V 8K
  __shared__ unsigned item_sh;
  char* Vsm = smem + 16384;
  const int tid = threadIdx.x;
  const int wid = tid >> 6, lane = tid & 63;
  const int ql = lane & 31, hi = lane >> 5;
  const int sw = lane & 7;              // LDS chunk swizzle key
  const bool causal = (maskp[0] != 0);

  for (;;) {
    if (tid == 0) item_sh = atomicAdd(wq, 1u);
    __syncthreads();                     // item visible; prior item's LDS reads done
    const unsigned item = item_sh;
    if (item >= 1024u) break;

    const int qt = causal ? (15 - (int)(item >> 6)) : (int)(item >> 6);  // longest first
    const int bh = (int)(item & 63u);
    const int b = bh >> 5, h = bh & 31;
    const int kvh = h >> 2;
    const int q0 = qt*128;
    const int qg = q0 + 32*wid + ql;        // this lane's global q row
    const int nt = causal ? (2*qt + 2) : (SEQ/64);

    // Q fragments (B-operand): lane holds Q[q=ql][d = 16dd + 8hi + j]
    const unsigned short* qbase = Q + (size_t)(b*SEQ + qg)*QKV_N + h*HEAD_DIM + 8*hi;
    bf16x8 qf[4];
    #pragma unroll
    for (int dd = 0; dd < 4; ++dd) qf[dd] = *(const bf16x8*)(qbase + 16*dd);

    f32x16 acc[2] = {};       // O^T: acc[dt] -> d = (r&3)+8*(r>>2)+4hi+32dt, q = ql
    float mrun = -1e30f, lrun = 0.f;

    // staging helpers (pre-swizzled global source, linear LDS dest)
    auto stageK = [&](int tile, int bufbase){
      const int s0s = tile*64;
      #pragma unroll
      for (int it = 0; it < 2; ++it) {
        int i = (wid*2+it)*64 + lane;     // 16B chunk index 0..511
        int s = i >> 3, c = i & 7;        // row, chunk-in-row
        async_copy16(Kb + (size_t)(b*SEQ + s0s + s)*QKV_N + kvh*HEAD_DIM + ((c ^ (s&7))*8),
                     smem + bufbase + (wid*2+it)*1024);
      }
    };
    auto stageV = [&](int tile){
      const int s0s = tile*64;
      #pragma unroll
      for (int it = 0; it < 2; ++it) {
        int i = (wid*2+it)*64 + lane;
        int s = i >> 3, c = i & 7;        // s = d-row of Vt tile
        async_copy16(Vt + ((size_t)(b*N_KV_HEAD + kvh)*HEAD_DIM + s)*SEQ + s0s + ((c ^ (s&7))*8),
                     Vsm + (wid*2+it)*1024);
      }
    };

    stageK(0, 0);
    stageV(0);
    asm volatile("s_waitcnt vmcnt(0)" ::: "memory");
    __syncthreads();

    for (int t = 0; t < nt; ++t) {
      const int s0 = t*64;
      const int cur = t & 1;
      const char* Kbuf = smem + cur*8192;

      if (t+1 < nt) stageK(t+1, (cur^1)*8192);

      // QK^T swapped: sa0/sa1 rows s = s0 + 32st + (r&3)+8*(r>>2)+4hi, col q = ql
      f32x16 sa0 = {}, sa1 = {};
      __builtin_amdgcn_s_setprio(1);
      #pragma unroll
      for (int dd = 0; dd < 4; ++dd) {
        int co = ((2*dd + hi) ^ sw) * 16;
        bf16x8 k0 = *(const bf16x8*)(Kbuf + ql*128 + co);
        bf16x8 k1 = *(const bf16x8*)(Kbuf + (ql+32)*128 + co);
        sa0 = mfma32(k0, qf[dd], sa0);
        sa1 = mfma32(k1, qf[dd], sa1);
      }
      __builtin_amdgcn_s_setprio(0);

      // causal mask (last two tiles of the item only)
      if (causal && t >= nt-2) {
        #pragma unroll
        for (int r = 0; r < 16; ++r) {
          int sl = (r&3) + 8*(r>>2) + 4*hi;
          if (s0 + sl > qg)      sa0[r] = -3.0e38f;
          if (s0 + 32 + sl > qg) sa1[r] = -3.0e38f;
        }
      }

      // in-lane max tree + cross-half shfl reduce
      float c4[4] = {-3.0e38f, -3.0e38f, -3.0e38f, -3.0e38f};
      #pragma unroll
      for (int r = 0; r < 16; ++r)
        c4[r&3] = fmaxf(c4[r&3], fmaxf(sa0[r], sa1[r]));
      float cmax = fmaxf(fmaxf(c4[0], c4[1]), fmaxf(c4[2], c4[3]));
      cmax = fmaxf(cmax, __shfl_xor(cmax, 32));

      if (!__all(cmax <= mrun + 8.0f)) {   // defer-max (T13), log2 domain
        float mnew = fmaxf(mrun, cmax);
        float r2 = exp2f(mrun - mnew);
        lrun *= r2;
        #pragma unroll
        for (int r = 0; r < 16; ++r) { acc[0][r] *= r2; acc[1][r] *= r2; }
        mrun = mnew;
      }
      float s4[4] = {0.f, 0.f, 0.f, 0.f};
      #pragma unroll
      for (int r = 0; r < 16; ++r) {
        float e0 = exp2f(sa0[r] - mrun);
        float e1 = exp2f(sa1[r] - mrun);
        sa0[r] = e0; sa1[r] = e1;
        s4[r&3] += e0 + e1;
      }
      float tsum = (s4[0] + s4[1]) + (s4[2] + s4[3]);
      tsum += __shfl_xor(tsum, 32);
      lrun += tsum;

      // P -> PV B-operand fragments, fully in-register
      bf16x8 pf0, pf1, pf2, pf3;        // ssub 0..3 (s 0-15,16-31,32-47,48-63)
      MKFRAG(sa0, 0, pf0); MKFRAG(sa0, 8, pf1);
      MKFRAG(sa1, 0, pf2); MKFRAG(sa1, 8, pf3);

      // K(t+1) + V(t) resident after this
      asm volatile("s_waitcnt vmcnt(0)" ::: "memory");
      __syncthreads();

      // PV: O^T += V^T * P^T
      __builtin_amdgcn_s_setprio(1);
      #pragma unroll
      for (int dt = 0; dt < 2; ++dt) {
        const char* vb = Vsm + (ql + 32*dt)*128;
        bf16x8 v0 = *(const bf16x8*)(vb + (((0+hi) ^ sw)*16));
        bf16x8 v1 = *(const bf16x8*)(vb + (((2+hi) ^ sw)*16));
        bf16x8 v2 = *(const bf16x8*)(vb + (((4+hi) ^ sw)*16));
        bf16x8 v3 = *(const bf16x8*)(vb + (((6+hi) ^ sw)*16));
        acc[dt] = mfma32(v0, pf0, acc[dt]);
        acc[dt] = mfma32(v1, pf1, acc[dt]);
        acc[dt] = mfma32(v2, pf2, acc[dt]);
        acc[dt] = mfma32(v3, pf3, acc[dt]);
      }
      __builtin_amdgcn_s_setprio(0);

      __syncthreads();                 // all Vsm readers done -> safe to restage
      if (t+1 < nt) stageV(t+1);       // drains at next iter's vmcnt(0)
    }

    // epilogue: O^T -> LDS [q][d] (bf16, swizzled; reuse K region) -> coalesced store
    float inv = 1.0f / lrun;
    char* osm = smem + wid*4096;       // per-wave 32 rows x 128B
    #pragma unroll
    for (int dt = 0; dt < 2; ++dt) {
      #pragma unroll
      for (int r = 0; r < 16; r += 2) {
        unsigned w = cvtpk(acc[dt][r]*inv, acc[dt][r+1]*inv);
        int chunk = (r>>2) + 4*dt;
        int byteo = ql*128 + ((chunk ^ (ql&7))*16) + 8*hi + ((r&2)<<1);
        *(unsigned*)(osm + byteo) = w;
      }
    }
    __syncthreads();
    #pragma unroll
    for (int it = 0; it < 4; ++it) {
      int idx = tid + 256*it;          // 0..1023: 128 rows x 8 chunks
      int row = idx >> 3, ch = idx & 7;
      uint4 v = *(const uint4*)(smem + (row>>5)*4096 + (row&31)*128 + ((ch ^ (row&7))*16));
      *(uint4*)(O + (size_t)(b*SEQ + q0 + row)*D_MODEL + h*HEAD_DIM + ch*8) = v;
    }
    // claim-barrier at loop top orders these reads before next item's staging
  }
}

extern "C" void kernel_launch(void* const* d_in, const int* in_sizes, int n_in,
                              void* d_out, int out_size, void* d_ws, size_t ws_size,
                              hipStream_t stream){
  const float* x  = (const float*)d_in[0];
  const float* Wq = (const float*)d_in[1];
  const float* Wk = (const float*)d_in[2];
  const float* Wv = (const float*)d_in[3];
  const float* Wo = (const float*)d_in[4];
  const int* maskp = (const int*)d_in[5];
  float* out = (float*)d_out;

  char* ws = (char*)d_ws;
  unsigned short* xb    = (unsigned short*)(ws);               // 16 MB [4096][2048]
  unsigned short* AO    = (unsigned short*)(ws);               // 16 MB (xb dead after QKV GEMM)
  unsigned short* Wqkvt = (unsigned short*)(ws + 16777216);    // 12 MB [3072][2048]
  unsigned short* Vt    = (unsigned short*)(ws + 16777216);    //  4 MB (Wqkvt dead after QKV GEMM)
  unsigned short* Wot   = (unsigned short*)(ws + 29360128);    //  8 MB [2048][2048]
  unsigned short* QKVb  = (unsigned short*)(ws + 37748736);    // 24 MB [4096][3072]
  float* ct = (float*)(ws + 62914560);                         // 256 KB [2048][32]
  float* st = (float*)(ws + 63176704);                         // 256 KB
  unsigned* wq = (unsigned*)(ws + 63438848);                   // 4 B work-queue counter

  hipMemsetAsync(wq, 0, 4, stream);    // reset claim counter every launch (graph-capturable)

  k_cvt_bf16<<<8192, 256, 0, stream>>>(x, xb, ROWS*D_MODEL/4);
  k_transpose_bf16<<<1024, 256, 0, stream>>>(Wq, Wqkvt,                          D_MODEL, 2048);
  k_transpose_bf16<<<256,  256, 0, stream>>>(Wk, Wqkvt + (size_t)2048*D_MODEL,   D_MODEL, 512);
  k_transpose_bf16<<<256,  256, 0, stream>>>(Wv, Wqkvt + (size_t)2560*D_MODEL,   D_MODEL, 512);
  k_transpose_bf16<<<1024, 256, 0, stream>>>(Wo, Wot, D_MODEL, 2048);
  k_rope_tables<<<SEQ*32/256, 256, 0, stream>>>(ct, st);

  // fused QKV projection: [4096][3072]
  k_gemm_bt<unsigned short><<<(4096/128)*(QKV_N/128), 256, 0, stream>>>(xb, Wqkvt, QKVb, 4096, QKV_N, 2048);

  // Q pre-scaled by 0.125*log2(e) so QK^T lands in log2 domain
  k_rope_apply<<<ROWS*N_HEAD/256,    256, 0, stream>>>(QKVb,        ct, st, N_HEAD,    QKV_N, 0.18033688011112042f);
  k_rope_apply<<<ROWS*N_KV_HEAD/256, 256, 0, stream>>>(QKVb + 2048, ct, st, N_KV_HEAD, QKV_N, 1.0f);

  k_transpose_v<<<BATCH*N_KV_HEAD*(SEQ/64), 256, 0, stream>>>(QKVb + 2560, Vt, QKV_N);

  // persistent blocks + dynamic queue: 768 blocks claim 1024 (b,h,qtile) items
  k_attn_mfma<<<768, 256, 0, stream>>>(QKVb, QKVb + 2048, Vt, AO, maskp, wq);

  k_gemm_bt<float><<<(4096/128)*(2048/128), 256, 0, stream>>>(AO, Wot, out, 4096, 2048, 2048);
}